// Round 1
// baseline (352.477 us; speedup 1.0000x reference)
//
#include <hip/hip_runtime.h>
#include <cstdint>
#include <cstddef>

typedef unsigned short u16;
typedef __attribute__((ext_vector_type(8))) short short8;
typedef __attribute__((ext_vector_type(4))) float f32x4;
typedef __attribute__((ext_vector_type(4))) float float4v;
typedef __attribute__((ext_vector_type(4))) u16 u16x4;

__device__ __forceinline__ u16 f2bf(float f) {
  union { float f; uint32_t u; } v; v.f = f;
  uint32_t u = v.u;
  return (u16)((u + 0x7FFFu + ((u >> 16) & 1u)) >> 16);
}
__device__ __forceinline__ float bf2f(u16 s) {
  union { uint32_t u; float f; } v; v.u = ((uint32_t)s) << 16; return v.f;
}

// ---------------- convert f32 -> bf16 ----------------
__global__ __launch_bounds__(256) void k_cvt(const float* __restrict__ in, u16* __restrict__ out, int n4) {
  int i = blockIdx.x * 256 + threadIdx.x;
  if (i >= n4) return;
  float4v v = *(const float4v*)(in + (size_t)i * 4);
  u16x4 o;
  #pragma unroll
  for (int j = 0; j < 4; j++) o[j] = f2bf(v[j]);
  *(u16x4*)(out + (size_t)i * 4) = o;
}

// ---------------- layernorm f32 -> bf16 (one block per row of 1024) ----------------
__global__ __launch_bounds__(256) void k_ln(const float* __restrict__ x, const float* __restrict__ g,
                                            const float* __restrict__ b, u16* __restrict__ out) {
  int row = blockIdx.x, tid = threadIdx.x;
  int wid = tid >> 6;
  const float* xr = x + (size_t)row * 1024;
  float4v v = *(const float4v*)(xr + tid * 4);
  float s = v[0] + v[1] + v[2] + v[3];
  float sq = v[0]*v[0] + v[1]*v[1] + v[2]*v[2] + v[3]*v[3];
  #pragma unroll
  for (int m = 1; m <= 32; m <<= 1) { s += __shfl_xor(s, m); sq += __shfl_xor(sq, m); }
  __shared__ float ss[4], ssq[4];
  if ((tid & 63) == 0) { ss[wid] = s; ssq[wid] = sq; }
  __syncthreads();
  s = ss[0] + ss[1] + ss[2] + ss[3];
  sq = ssq[0] + ssq[1] + ssq[2] + ssq[3];
  float mu = s * (1.0f/1024.0f);
  float var = sq * (1.0f/1024.0f) - mu*mu;
  float rs = rsqrtf(var + 1e-5f);
  u16x4 o;
  #pragma unroll
  for (int j = 0; j < 4; j++) {
    float y = (v[j] - mu) * rs * g[tid*4+j] + b[tid*4+j];
    o[j] = f2bf(y);
  }
  *(u16x4*)(out + (size_t)row * 1024 + tid * 4) = o;
}

// ---------------- GEMM: C[M,N] = A[M,K] @ B[N,K]^T  (bf16 in, fp32 acc) ----------------
// EPI: 0=f32 store, 1=f32 store + resid, 2=bf16 store gelu(acc+bias), 3=f32 acc+bias+resid, 4=bf16 plain
template<int EPI>
__global__ __launch_bounds__(256) void k_gemm(const u16* __restrict__ A, const u16* __restrict__ B,
                                              const float* __restrict__ bias, const float* __restrict__ resid,
                                              float* __restrict__ Cf, u16* __restrict__ Cb,
                                              int M, int N, int K) {
  __shared__ __align__(16) u16 As[128*64];
  __shared__ __align__(16) u16 Bs[128*64];
  int tid = threadIdx.x;
  int m0 = blockIdx.y * 128, n0 = blockIdx.x * 128;
  int wid = tid >> 6, lane = tid & 63;
  int wr = wid >> 1, wc = wid & 1;
  int l15 = lane & 15, l16 = lane >> 4;
  f32x4 acc[4][4] = {};
  for (int kb = 0; kb < K; kb += 64) {
    #pragma unroll
    for (int i = 0; i < 4; i++) {
      int chunk = tid + 256*i;
      int row = chunk >> 3, slot = chunk & 7;
      int dst = row*64 + ((slot ^ (row & 7)) * 8);
      short8 va = *(const short8*)(A + (size_t)(m0+row)*K + kb + slot*8);
      short8 vb = *(const short8*)(B + (size_t)(n0+row)*K + kb + slot*8);
      *(short8*)&As[dst] = va;
      *(short8*)&Bs[dst] = vb;
    }
    __syncthreads();
    #pragma unroll
    for (int ks = 0; ks < 2; ks++) {
      short8 af[4], bfr[4];
      #pragma unroll
      for (int m = 0; m < 4; m++) {
        int row = wr*64 + m*16 + l15;
        af[m] = *(const short8*)&As[row*64 + (((ks*4 + l16) ^ (row & 7)) * 8)];
      }
      #pragma unroll
      for (int n = 0; n < 4; n++) {
        int row = wc*64 + n*16 + l15;
        bfr[n] = *(const short8*)&Bs[row*64 + (((ks*4 + l16) ^ (row & 7)) * 8)];
      }
      #pragma unroll
      for (int m = 0; m < 4; m++)
        #pragma unroll
        for (int n = 0; n < 4; n++)
          acc[m][n] = __builtin_amdgcn_mfma_f32_16x16x32_bf16(af[m], bfr[n], acc[m][n], 0, 0, 0);
    }
    __syncthreads();
  }
  #pragma unroll
  for (int m = 0; m < 4; m++) {
    #pragma unroll
    for (int n = 0; n < 4; n++) {
      int col = n0 + wc*64 + n*16 + l15;
      #pragma unroll
      for (int r = 0; r < 4; r++) {
        int row = m0 + wr*64 + m*16 + l16*4 + r;
        float v = acc[m][n][r];
        if constexpr (EPI == 1) v += resid[(size_t)row*N + col];
        if constexpr (EPI == 2) { v += bias[col]; v = 0.5f*v*(1.0f + erff(v*0.70710678118f)); }
        if constexpr (EPI == 3) v += bias[col] + resid[(size_t)row*N + col];
        if constexpr (EPI == 2 || EPI == 4) Cb[(size_t)row*N + col] = f2bf(v);
        else Cf[(size_t)row*N + col] = v;
      }
    }
  }
}

// ---------------- prep: l2norm q,k (fold temp into q), V -> V^T ----------------
// qkv_bf: [4096, 3072] bf16. Outputs: Qn,Kn [bh][2048][64], Vt [bh][64][2048]
__global__ __launch_bounds__(256) void k_prep(const u16* __restrict__ qkv, const float* __restrict__ temp,
                                              u16* __restrict__ Qn, u16* __restrict__ Kn, u16* __restrict__ Vt) {
  int grp = blockIdx.x, bh = blockIdx.y;
  int b = bh >> 4, h = bh & 15;
  int tid = threadIdx.x, wid = tid >> 6, lane = tid & 63;
  int n0 = grp * 64;
  __shared__ __align__(16) u16 vs[64*64];
  float tmp = temp[h];
  for (int j = 0; j < 16; j++) {
    int tl = wid + 4*j;
    size_t roff = (size_t)((b*2048) + n0 + tl) * 3072;
    float q = bf2f(qkv[roff + h*64 + lane]);
    float k = bf2f(qkv[roff + 1024 + h*64 + lane]);
    u16 vraw = qkv[roff + 2048 + h*64 + lane];
    float sq = q*q, sk = k*k;
    #pragma unroll
    for (int m = 1; m <= 32; m <<= 1) { sq += __shfl_xor(sq, m); sk += __shfl_xor(sk, m); }
    float qs = tmp / fmaxf(sqrtf(sq), 1e-12f);
    float ksc = 1.0f / fmaxf(sqrtf(sk), 1e-12f);
    size_t obase = ((size_t)bh*2048 + n0 + tl)*64 + lane;
    Qn[obase] = f2bf(q * qs);
    Kn[obase] = f2bf(k * ksc);
    vs[tl*64 + lane] = vraw;
  }
  __syncthreads();
  int d = tid & 63, chunk = tid >> 6;
  u16 vals[16];
  #pragma unroll
  for (int jj = 0; jj < 16; jj++) vals[jj] = vs[(chunk*16 + jj)*64 + d];
  short8 w0, w1v;
  #pragma unroll
  for (int j = 0; j < 8; j++) { w0[j] = (short)vals[j]; w1v[j] = (short)vals[8+j]; }
  size_t vo = ((size_t)bh*64 + d)*2048 + n0 + chunk*16;
  *(short8*)(Vt + vo) = w0;
  *(short8*)(Vt + vo + 8) = w1v;
}

// ---------------- flash attention: 64 q-rows per block, 4 waves x 16 rows ----------------
__global__ __launch_bounds__(256) void k_attn(const u16* __restrict__ Qn, const u16* __restrict__ Kn,
                                              const u16* __restrict__ Vt, u16* __restrict__ Out) {
  __shared__ __align__(16) u16 Ks[64*64];
  __shared__ __align__(16) u16 Vs[64*64];
  __shared__ __align__(16) u16 Ps[4*16*64];
  int qg = blockIdx.x, bh = blockIdx.y;
  int tid = threadIdx.x, wid = tid >> 6, lane = tid & 63;
  int l15 = lane & 15, l16 = lane >> 4;
  size_t base = (size_t)bh * 2048 * 64;
  int q0 = qg*64 + wid*16;
  short8 qf[2];
  #pragma unroll
  for (int ks = 0; ks < 2; ks++)
    qf[ks] = *(const short8*)(Qn + base + (size_t)(q0 + l15)*64 + ks*32 + l16*8);
  f32x4 o[4] = {};
  float mrow[4] = {-1e30f, -1e30f, -1e30f, -1e30f};
  float lrow[4] = {0.f, 0.f, 0.f, 0.f};
  u16* Pw = Ps + wid*16*64;
  for (int kv = 0; kv < 2048; kv += 64) {
    #pragma unroll
    for (int i = 0; i < 2; i++) {
      int chunk = tid + 256*i;
      int row = chunk >> 3, slot = chunk & 7;
      int dst = row*64 + ((slot ^ (row&7))*8);
      short8 kvv = *(const short8*)(Kn + base + (size_t)(kv + row)*64 + slot*8);
      short8 vvv = *(const short8*)(Vt + ((size_t)bh*64 + row)*2048 + kv + slot*8);
      *(short8*)&Ks[dst] = kvv;
      *(short8*)&Vs[dst] = vvv;
    }
    __syncthreads();
    f32x4 s[4] = {};
    #pragma unroll
    for (int ks = 0; ks < 2; ks++) {
      short8 kf[4];
      #pragma unroll
      for (int nt = 0; nt < 4; nt++) {
        int row = nt*16 + l15;
        kf[nt] = *(const short8*)&Ks[row*64 + (((ks*4 + l16) ^ (row&7))*8)];
      }
      #pragma unroll
      for (int nt = 0; nt < 4; nt++)
        s[nt] = __builtin_amdgcn_mfma_f32_16x16x32_bf16(qf[ks], kf[nt], s[nt], 0, 0, 0);
    }
    float scl[4];
    #pragma unroll
    for (int r = 0; r < 4; r++) {
      float mx = fmaxf(fmaxf(s[0][r], s[1][r]), fmaxf(s[2][r], s[3][r]));
      mx = fmaxf(mx, __shfl_xor(mx, 1));
      mx = fmaxf(mx, __shfl_xor(mx, 2));
      mx = fmaxf(mx, __shfl_xor(mx, 4));
      mx = fmaxf(mx, __shfl_xor(mx, 8));
      float mn = fmaxf(mrow[r], mx);
      scl[r] = __expf(mrow[r] - mn);
      mrow[r] = mn;
    }
    float psum[4] = {0.f, 0.f, 0.f, 0.f};
    #pragma unroll
    for (int nt = 0; nt < 4; nt++) {
      #pragma unroll
      for (int r = 0; r < 4; r++) {
        float p = __expf(s[nt][r] - mrow[r]);
        psum[r] += p;
        int rloc = l16*4 + r, col = nt*16 + l15;
        Pw[rloc*64 + (((col >> 3) ^ (rloc & 7))*8) + (col & 7)] = f2bf(p);
      }
    }
    #pragma unroll
    for (int r = 0; r < 4; r++) {
      float t = psum[r];
      t += __shfl_xor(t, 1); t += __shfl_xor(t, 2);
      t += __shfl_xor(t, 4); t += __shfl_xor(t, 8);
      lrow[r] = lrow[r]*scl[r] + t;
    }
    #pragma unroll
    for (int dt = 0; dt < 4; dt++)
      #pragma unroll
      for (int r = 0; r < 4; r++) o[dt][r] *= scl[r];
    asm volatile("s_waitcnt lgkmcnt(0)" ::: "memory");
    __builtin_amdgcn_sched_barrier(0);
    #pragma unroll
    for (int ks = 0; ks < 2; ks++) {
      int prow = l15;
      short8 pf = *(const short8*)&Pw[prow*64 + (((ks*4 + l16) ^ (prow&7))*8)];
      short8 vf[4];
      #pragma unroll
      for (int dt = 0; dt < 4; dt++) {
        int row = dt*16 + l15;
        vf[dt] = *(const short8*)&Vs[row*64 + (((ks*4 + l16) ^ (row&7))*8)];
      }
      #pragma unroll
      for (int dt = 0; dt < 4; dt++)
        o[dt] = __builtin_amdgcn_mfma_f32_16x16x32_bf16(pf, vf[dt], o[dt], 0, 0, 0);
    }
    __syncthreads();
  }
  int b = bh >> 4, h = bh & 15;
  #pragma unroll
  for (int dt = 0; dt < 4; dt++) {
    #pragma unroll
    for (int r = 0; r < 4; r++) {
      int tok = q0 + l16*4 + r;
      int col = h*64 + dt*16 + l15;
      Out[((size_t)(b*2048 + tok))*1024 + col] = f2bf(o[dt][r] / lrow[r]);
    }
  }
}

// ---------------- workspace layout (bytes) ----------------
static constexpr size_t OFF_WQKV  = 0;                         // 3072*1024*2
static constexpr size_t OFF_WPROJ = OFF_WQKV  + 6291456;       // 1024*1024*2
static constexpr size_t OFF_W1    = OFF_WPROJ + 2097152;       // 4096*1024*2
static constexpr size_t OFF_W2    = OFF_W1    + 8388608;       // 1024*4096*2
static constexpr size_t OFF_HBF   = OFF_W2    + 8388608;       // 4096*1024*2
static constexpr size_t OFF_H2BF  = OFF_HBF   + 8388608;
static constexpr size_t OFF_QKVBF = OFF_H2BF  + 8388608;       // 4096*3072*2
static constexpr size_t OFF_QN    = OFF_QKVBF + 25165824;      // 32*2048*64*2
static constexpr size_t OFF_KN    = OFF_QN    + 8388608;
static constexpr size_t OFF_VT    = OFF_KN    + 8388608;
static constexpr size_t OFF_AOUT  = OFF_VT    + 8388608;
static constexpr size_t OFF_X1    = OFF_AOUT  + 8388608;       // 4096*1024*4
static constexpr size_t OFF_HID   = OFF_X1    + 16777216;      // 4096*4096*2

extern "C" void kernel_launch(void* const* d_in, const int* in_sizes, int n_in,
                              void* d_out, int out_size, void* d_ws, size_t ws_size,
                              hipStream_t stream) {
  (void)in_sizes; (void)n_in; (void)out_size; (void)ws_size;
  const float* x     = (const float*)d_in[0];
  const float* ln1g  = (const float*)d_in[1];
  const float* ln1b  = (const float*)d_in[2];
  const float* wqkv  = (const float*)d_in[3];
  const float* wproj = (const float*)d_in[4];
  const float* temp  = (const float*)d_in[5];
  const float* ln2g  = (const float*)d_in[6];
  const float* ln2b  = (const float*)d_in[7];
  const float* w1    = (const float*)d_in[8];
  const float* b1    = (const float*)d_in[9];
  const float* w2    = (const float*)d_in[10];
  const float* b2    = (const float*)d_in[11];

  char* ws = (char*)d_ws;
  u16* wqkv_bf  = (u16*)(ws + OFF_WQKV);
  u16* wproj_bf = (u16*)(ws + OFF_WPROJ);
  u16* w1_bf    = (u16*)(ws + OFF_W1);
  u16* w2_bf    = (u16*)(ws + OFF_W2);
  u16* h_bf     = (u16*)(ws + OFF_HBF);
  u16* h2_bf    = (u16*)(ws + OFF_H2BF);
  u16* qkv_bf   = (u16*)(ws + OFF_QKVBF);
  u16* Qn       = (u16*)(ws + OFF_QN);
  u16* Kn       = (u16*)(ws + OFF_KN);
  u16* Vt       = (u16*)(ws + OFF_VT);
  u16* aout_bf  = (u16*)(ws + OFF_AOUT);
  float* x1     = (float*)(ws + OFF_X1);
  u16* hid_bf   = (u16*)(ws + OFF_HID);
  float* outf   = (float*)d_out;

  // weight conversion (every call: deterministic, ~10us total)
  k_cvt<<<3072, 256, 0, stream>>>(wqkv,  wqkv_bf,  786432);
  k_cvt<<<1024, 256, 0, stream>>>(wproj, wproj_bf, 262144);
  k_cvt<<<4096, 256, 0, stream>>>(w1,    w1_bf,    1048576);
  k_cvt<<<4096, 256, 0, stream>>>(w2,    w2_bf,    1048576);

  // LN1
  k_ln<<<4096, 256, 0, stream>>>(x, ln1g, ln1b, h_bf);
  // qkv = h @ w_qkv^T  -> bf16 [4096,3072]
  k_gemm<4><<<dim3(24, 32), 256, 0, stream>>>(h_bf, wqkv_bf, nullptr, nullptr, nullptr, qkv_bf, 4096, 3072, 1024);
  // l2norm q/k + temp, V transpose
  k_prep<<<dim3(32, 32), 256, 0, stream>>>(qkv_bf, temp, Qn, Kn, Vt);
  // attention
  k_attn<<<dim3(32, 32), 256, 0, stream>>>(Qn, Kn, Vt, aout_bf);
  // x1 = x + attn_out @ w_proj^T
  k_gemm<1><<<dim3(8, 32), 256, 0, stream>>>(aout_bf, wproj_bf, nullptr, x, x1, nullptr, 4096, 1024, 1024);
  // LN2
  k_ln<<<4096, 256, 0, stream>>>(x1, ln2g, ln2b, h2_bf);
  // hid = gelu(h2 @ w1^T + b1) -> bf16 [4096,4096]
  k_gemm<2><<<dim3(32, 32), 256, 0, stream>>>(h2_bf, w1_bf, b1, nullptr, nullptr, hid_bf, 4096, 4096, 1024);
  // out = x1 + hid @ w2^T + b2 -> f32
  k_gemm<3><<<dim3(8, 32), 256, 0, stream>>>(hid_bf, w2_bf, b2, x1, outf, nullptr, 4096, 1024, 4096);
}

// Round 2
// 302.865 us; speedup vs baseline: 1.1638x; 1.1638x over previous
//
#include <hip/hip_runtime.h>
#include <cstdint>
#include <cstddef>

typedef unsigned short u16;
typedef __attribute__((ext_vector_type(8))) short short8;
typedef __attribute__((ext_vector_type(4))) float f32x4;
typedef __attribute__((ext_vector_type(4))) float float4v;
typedef __attribute__((ext_vector_type(4))) u16 u16x4;

__device__ __forceinline__ u16 f2bf(float f) {
  union { float f; uint32_t u; } v; v.f = f;
  uint32_t u = v.u;
  return (u16)((u + 0x7FFFu + ((u >> 16) & 1u)) >> 16);
}
__device__ __forceinline__ float bf2f(u16 s) {
  union { uint32_t u; float f; } v; v.u = ((uint32_t)s) << 16; return v.f;
}

__device__ __forceinline__ float fast_exp2(float x) {
#if __has_builtin(__builtin_amdgcn_exp2f)
  return __builtin_amdgcn_exp2f(x);
#else
  return exp2f(x);
#endif
}

// async global->LDS, 16B per lane, dest = wave-uniform base + lane*16
__device__ __forceinline__ void gload16(const u16* g, u16* l) {
  __builtin_amdgcn_global_load_lds((const __attribute__((address_space(1))) void*)g,
                                   (__attribute__((address_space(3))) void*)l,
                                   16, 0, 0);
}

// ---------------- convert f32 -> bf16 ----------------
__global__ __launch_bounds__(256) void k_cvt(const float* __restrict__ in, u16* __restrict__ out, int n4) {
  int i = blockIdx.x * 256 + threadIdx.x;
  if (i >= n4) return;
  float4v v = *(const float4v*)(in + (size_t)i * 4);
  u16x4 o;
  #pragma unroll
  for (int j = 0; j < 4; j++) o[j] = f2bf(v[j]);
  *(u16x4*)(out + (size_t)i * 4) = o;
}

// ---------------- layernorm f32 -> bf16 (one block per row of 1024) ----------------
__global__ __launch_bounds__(256) void k_ln(const float* __restrict__ x, const float* __restrict__ g,
                                            const float* __restrict__ b, u16* __restrict__ out) {
  int row = blockIdx.x, tid = threadIdx.x;
  int wid = tid >> 6;
  const float* xr = x + (size_t)row * 1024;
  float4v v = *(const float4v*)(xr + tid * 4);
  float s = v[0] + v[1] + v[2] + v[3];
  float sq = v[0]*v[0] + v[1]*v[1] + v[2]*v[2] + v[3]*v[3];
  #pragma unroll
  for (int m = 1; m <= 32; m <<= 1) { s += __shfl_xor(s, m); sq += __shfl_xor(sq, m); }
  __shared__ float ss[4], ssq[4];
  if ((tid & 63) == 0) { ss[wid] = s; ssq[wid] = sq; }
  __syncthreads();
  s = ss[0] + ss[1] + ss[2] + ss[3];
  sq = ssq[0] + ssq[1] + ssq[2] + ssq[3];
  float mu = s * (1.0f/1024.0f);
  float var = sq * (1.0f/1024.0f) - mu*mu;
  float rs = rsqrtf(var + 1e-5f);
  u16x4 o;
  #pragma unroll
  for (int j = 0; j < 4; j++) {
    float y = (v[j] - mu) * rs * g[tid*4+j] + b[tid*4+j];
    o[j] = f2bf(y);
  }
  *(u16x4*)(out + (size_t)row * 1024 + tid * 4) = o;
}

// ---------------- GEMM: C[M,N] = A[M,K] @ B[N,K]^T  (bf16 in, fp32 acc) ----------------
// Staging: global_load_lds width=16, linear LDS dest, inverse-XOR-swizzled global source.
// EPI: 1=f32 store + resid, 2=bf16 store gelu(acc+bias), 3=f32 acc+bias+resid, 4=bf16 plain
template<int EPI>
__global__ __launch_bounds__(256) void k_gemm(const u16* __restrict__ A, const u16* __restrict__ B,
                                              const float* __restrict__ bias, const float* __restrict__ resid,
                                              float* __restrict__ Cf, u16* __restrict__ Cb,
                                              int M, int N, int K) {
  __shared__ __align__(16) u16 As[128*64];
  __shared__ __align__(16) u16 Bs[128*64];
  int tid = threadIdx.x;
  int m0 = blockIdx.y * 128, n0 = blockIdx.x * 128;
  int wid = tid >> 6, lane = tid & 63;
  int wr = wid >> 1, wc = wid & 1;
  int l15 = lane & 15, l16 = lane >> 4;
  f32x4 acc[4][4] = {};
  for (int kb = 0; kb < K; kb += 64) {
    #pragma unroll
    for (int i = 0; i < 4; i++) {
      int base_row = wid*32 + i*8;
      int row = base_row + (lane >> 3);
      int gslot = (lane & 7) ^ (row & 7);
      gload16(A + (size_t)(m0+row)*K + kb + gslot*8, &As[base_row*64]);
      gload16(B + (size_t)(n0+row)*K + kb + gslot*8, &Bs[base_row*64]);
    }
    __syncthreads();
    #pragma unroll
    for (int ks = 0; ks < 2; ks++) {
      short8 af[4], bfr[4];
      #pragma unroll
      for (int m = 0; m < 4; m++) {
        int row = wr*64 + m*16 + l15;
        af[m] = *(const short8*)&As[row*64 + (((ks*4 + l16) ^ (row & 7)) * 8)];
      }
      #pragma unroll
      for (int n = 0; n < 4; n++) {
        int row = wc*64 + n*16 + l15;
        bfr[n] = *(const short8*)&Bs[row*64 + (((ks*4 + l16) ^ (row & 7)) * 8)];
      }
      #pragma unroll
      for (int m = 0; m < 4; m++)
        #pragma unroll
        for (int n = 0; n < 4; n++)
          acc[m][n] = __builtin_amdgcn_mfma_f32_16x16x32_bf16(af[m], bfr[n], acc[m][n], 0, 0, 0);
    }
    __syncthreads();
  }
  #pragma unroll
  for (int m = 0; m < 4; m++) {
    #pragma unroll
    for (int n = 0; n < 4; n++) {
      int col = n0 + wc*64 + n*16 + l15;
      #pragma unroll
      for (int r = 0; r < 4; r++) {
        int row = m0 + wr*64 + m*16 + l16*4 + r;
        float v = acc[m][n][r];
        if constexpr (EPI == 1) v += resid[(size_t)row*N + col];
        if constexpr (EPI == 2) { v += bias[col]; v = 0.5f*v*(1.0f + erff(v*0.70710678118f)); }
        if constexpr (EPI == 3) v += bias[col] + resid[(size_t)row*N + col];
        if constexpr (EPI == 2 || EPI == 4) Cb[(size_t)row*N + col] = f2bf(v);
        else Cf[(size_t)row*N + col] = v;
      }
    }
  }
}

// ---------------- prep: l2norm q,k (fold temp*log2e into q), V -> V^T ----------------
__global__ __launch_bounds__(256) void k_prep(const u16* __restrict__ qkv, const float* __restrict__ temp,
                                              u16* __restrict__ Qn, u16* __restrict__ Kn, u16* __restrict__ Vt) {
  int grp = blockIdx.x, bh = blockIdx.y;
  int b = bh >> 4, h = bh & 15;
  int tid = threadIdx.x, wid = tid >> 6, lane = tid & 63;
  int n0 = grp * 64;
  __shared__ __align__(16) u16 vs[64*64];
  float tmp = temp[h] * 1.44269504f;   // fold log2e for exp2-domain softmax
  for (int j = 0; j < 16; j++) {
    int tl = wid + 4*j;
    size_t roff = (size_t)((b*2048) + n0 + tl) * 3072;
    float q = bf2f(qkv[roff + h*64 + lane]);
    float k = bf2f(qkv[roff + 1024 + h*64 + lane]);
    u16 vraw = qkv[roff + 2048 + h*64 + lane];
    float sq = q*q, sk = k*k;
    #pragma unroll
    for (int m = 1; m <= 32; m <<= 1) { sq += __shfl_xor(sq, m); sk += __shfl_xor(sk, m); }
    float qs = tmp / fmaxf(sqrtf(sq), 1e-12f);
    float ksc = 1.0f / fmaxf(sqrtf(sk), 1e-12f);
    size_t obase = ((size_t)bh*2048 + n0 + tl)*64 + lane;
    Qn[obase] = f2bf(q * qs);
    Kn[obase] = f2bf(k * ksc);
    vs[tl*64 + lane] = vraw;
  }
  __syncthreads();
  int d = tid & 63, chunk = tid >> 6;
  u16 vals[16];
  #pragma unroll
  for (int jj = 0; jj < 16; jj++) vals[jj] = vs[(chunk*16 + jj)*64 + d];
  short8 w0, w1v;
  #pragma unroll
  for (int j = 0; j < 8; j++) { w0[j] = (short)vals[j]; w1v[j] = (short)vals[8+j]; }
  size_t vo = ((size_t)bh*64 + d)*2048 + n0 + chunk*16;
  *(short8*)(Vt + vo) = w0;
  *(short8*)(Vt + vo + 8) = w1v;
}

// ---------------- flash attention, swapped-QK^T, fixed-max softmax ----------------
// Scores bounded: |q_hat . k_hat| <= 1  =>  s' = temp*log2e*(q.k) <= m2 = |temp|*log2e.
// p = exp2(s' - m2); the e^{-m2} constant cancels in p/l exactly.
__global__ __launch_bounds__(256) void k_attn(const u16* __restrict__ Qn, const u16* __restrict__ Kn,
                                              const u16* __restrict__ Vt, const float* __restrict__ temp,
                                              u16* __restrict__ Out) {
  __shared__ __align__(16) u16 Ks[64*64];
  __shared__ __align__(16) u16 Vs[64*64];
  __shared__ __align__(16) u16 Ps[4*16*64];
  int qg = blockIdx.x, bh = blockIdx.y;
  int b = bh >> 4, h = bh & 15;
  int tid = threadIdx.x, wid = tid >> 6, lane = tid & 63;
  int l15 = lane & 15, l16 = lane >> 4;
  size_t base = (size_t)bh * 2048 * 64;
  size_t vbase = (size_t)bh * 64 * 2048;
  int q0 = qg*64 + wid*16;
  float m2 = fabsf(temp[h]) * 1.44269504f;
  short8 qf[2];
  #pragma unroll
  for (int ks = 0; ks < 2; ks++)
    qf[ks] = *(const short8*)(Qn + base + (size_t)(q0 + l15)*64 + ks*32 + l16*8);
  f32x4 o[4] = {};
  float lrow = 0.f;
  u16* Pw = Ps + wid*16*64;
  uint32_t* Pw32 = (uint32_t*)Pw;
  for (int kv0 = 0; kv0 < 2048; kv0 += 64) {
    // stage K,V via global_load_lds (linear dest, pre-swizzled source)
    #pragma unroll
    for (int i = 0; i < 2; i++) {
      int base_row = wid*16 + i*8;
      int row = base_row + (lane >> 3);
      int gslot = (lane & 7) ^ (row & 7);
      gload16(Kn + base + (size_t)(kv0 + row)*64 + gslot*8, &Ks[base_row*64]);
      gload16(Vt + vbase + (size_t)row*2048 + kv0 + gslot*8, &Vs[base_row*64]);
    }
    __syncthreads();
    // S^T = K . Q^T : lane holds q = l15, kv = nt*16 + l16*4 + r
    f32x4 s[4] = {};
    #pragma unroll
    for (int ks = 0; ks < 2; ks++) {
      short8 kf[4];
      #pragma unroll
      for (int nt = 0; nt < 4; nt++) {
        int row = nt*16 + l15;
        kf[nt] = *(const short8*)&Ks[row*64 + (((ks*4 + l16) ^ (row&7))*8)];
      }
      #pragma unroll
      for (int nt = 0; nt < 4; nt++)
        s[nt] = __builtin_amdgcn_mfma_f32_16x16x32_bf16(kf[nt], qf[ks], s[nt], 0, 0, 0);
    }
    // fixed-max softmax: p = exp2(s - m2); pack pairs -> P^T rows (q-major) in LDS
    float tsum = 0.f;
    #pragma unroll
    for (int nt = 0; nt < 4; nt++) {
      #pragma unroll
      for (int rp = 0; rp < 2; rp++) {
        float p0 = fast_exp2(s[nt][2*rp]   - m2);
        float p1 = fast_exp2(s[nt][2*rp+1] - m2);
        tsum += p0 + p1;
        uint32_t pk;
        asm("v_cvt_pk_bf16_f32 %0, %1, %2" : "=v"(pk) : "v"(p0), "v"(p1));
        int w = nt*8 + l16*2 + rp;
        int slot = w >> 2;
        Pw32[l15*32 + ((slot ^ (l15 & 7))*4) + (w & 3)] = pk;
      }
    }
    lrow += tsum;
    asm volatile("s_waitcnt lgkmcnt(0)" ::: "memory");
    __builtin_amdgcn_sched_barrier(0);
    // O^T += V^T . P^T : A = V^T rows (d), B = P^T cols (q)
    #pragma unroll
    for (int ks = 0; ks < 2; ks++) {
      short8 pf = *(const short8*)&Pw[l15*64 + (((ks*4 + l16) ^ (l15&7))*8)];
      short8 vf[4];
      #pragma unroll
      for (int dt = 0; dt < 4; dt++) {
        int row = dt*16 + l15;
        vf[dt] = *(const short8*)&Vs[row*64 + (((ks*4 + l16) ^ (row&7))*8)];
      }
      #pragma unroll
      for (int dt = 0; dt < 4; dt++)
        o[dt] = __builtin_amdgcn_mfma_f32_16x16x32_bf16(vf[dt], pf, o[dt], 0, 0, 0);
    }
    __syncthreads();
  }
  // row sum: lanes sharing l15 hold disjoint kv partials
  lrow += __shfl_xor(lrow, 16);
  lrow += __shfl_xor(lrow, 32);
  float rl = 1.0f / lrow;
  int tok = b*2048 + q0 + l15;
  #pragma unroll
  for (int dt = 0; dt < 4; dt++) {
    u16x4 ov;
    #pragma unroll
    for (int r = 0; r < 4; r++) ov[r] = f2bf(o[dt][r] * rl);
    *(u16x4*)(Out + (size_t)tok*1024 + h*64 + dt*16 + l16*4) = ov;
  }
}

// ---------------- workspace layout (bytes) ----------------
static constexpr size_t OFF_WQKV  = 0;                         // 3072*1024*2
static constexpr size_t OFF_WPROJ = OFF_WQKV  + 6291456;       // 1024*1024*2
static constexpr size_t OFF_W1    = OFF_WPROJ + 2097152;       // 4096*1024*2
static constexpr size_t OFF_W2    = OFF_W1    + 8388608;       // 1024*4096*2
static constexpr size_t OFF_HBF   = OFF_W2    + 8388608;       // 4096*1024*2
static constexpr size_t OFF_H2BF  = OFF_HBF   + 8388608;
static constexpr size_t OFF_QKVBF = OFF_H2BF  + 8388608;       // 4096*3072*2
static constexpr size_t OFF_QN    = OFF_QKVBF + 25165824;      // 32*2048*64*2
static constexpr size_t OFF_KN    = OFF_QN    + 8388608;
static constexpr size_t OFF_VT    = OFF_KN    + 8388608;
static constexpr size_t OFF_AOUT  = OFF_VT    + 8388608;
static constexpr size_t OFF_X1    = OFF_AOUT  + 8388608;       // 4096*1024*4
static constexpr size_t OFF_HID   = OFF_X1    + 16777216;      // 4096*4096*2

extern "C" void kernel_launch(void* const* d_in, const int* in_sizes, int n_in,
                              void* d_out, int out_size, void* d_ws, size_t ws_size,
                              hipStream_t stream) {
  (void)in_sizes; (void)n_in; (void)out_size; (void)ws_size;
  const float* x     = (const float*)d_in[0];
  const float* ln1g  = (const float*)d_in[1];
  const float* ln1b  = (const float*)d_in[2];
  const float* wqkv  = (const float*)d_in[3];
  const float* wproj = (const float*)d_in[4];
  const float* temp  = (const float*)d_in[5];
  const float* ln2g  = (const float*)d_in[6];
  const float* ln2b  = (const float*)d_in[7];
  const float* w1    = (const float*)d_in[8];
  const float* b1    = (const float*)d_in[9];
  const float* w2    = (const float*)d_in[10];
  const float* b2    = (const float*)d_in[11];

  char* ws = (char*)d_ws;
  u16* wqkv_bf  = (u16*)(ws + OFF_WQKV);
  u16* wproj_bf = (u16*)(ws + OFF_WPROJ);
  u16* w1_bf    = (u16*)(ws + OFF_W1);
  u16* w2_bf    = (u16*)(ws + OFF_W2);
  u16* h_bf     = (u16*)(ws + OFF_HBF);
  u16* h2_bf    = (u16*)(ws + OFF_H2BF);
  u16* qkv_bf   = (u16*)(ws + OFF_QKVBF);
  u16* Qn       = (u16*)(ws + OFF_QN);
  u16* Kn       = (u16*)(ws + OFF_KN);
  u16* Vt       = (u16*)(ws + OFF_VT);
  u16* aout_bf  = (u16*)(ws + OFF_AOUT);
  float* x1     = (float*)(ws + OFF_X1);
  u16* hid_bf   = (u16*)(ws + OFF_HID);
  float* outf   = (float*)d_out;

  k_cvt<<<3072, 256, 0, stream>>>(wqkv,  wqkv_bf,  786432);
  k_cvt<<<1024, 256, 0, stream>>>(wproj, wproj_bf, 262144);
  k_cvt<<<4096, 256, 0, stream>>>(w1,    w1_bf,    1048576);
  k_cvt<<<4096, 256, 0, stream>>>(w2,    w2_bf,    1048576);

  k_ln<<<4096, 256, 0, stream>>>(x, ln1g, ln1b, h_bf);
  k_gemm<4><<<dim3(24, 32), 256, 0, stream>>>(h_bf, wqkv_bf, nullptr, nullptr, nullptr, qkv_bf, 4096, 3072, 1024);
  k_prep<<<dim3(32, 32), 256, 0, stream>>>(qkv_bf, temp, Qn, Kn, Vt);
  k_attn<<<dim3(32, 32), 256, 0, stream>>>(Qn, Kn, Vt, temp, aout_bf);
  k_gemm<1><<<dim3(8, 32), 256, 0, stream>>>(aout_bf, wproj_bf, nullptr, x, x1, nullptr, 4096, 1024, 1024);
  k_ln<<<4096, 256, 0, stream>>>(x1, ln2g, ln2b, h2_bf);
  k_gemm<2><<<dim3(32, 32), 256, 0, stream>>>(h2_bf, w1_bf, b1, nullptr, nullptr, hid_bf, 4096, 4096, 1024);
  k_gemm<3><<<dim3(8, 32), 256, 0, stream>>>(hid_bf, w2_bf, b2, x1, outf, nullptr, 4096, 1024, 4096);
}

// Round 3
// 279.591 us; speedup vs baseline: 1.2607x; 1.0832x over previous
//
#include <hip/hip_runtime.h>
#include <cstdint>
#include <cstddef>

typedef unsigned short u16;
typedef __attribute__((ext_vector_type(8))) short short8;
typedef __attribute__((ext_vector_type(4))) float f32x4;
typedef __attribute__((ext_vector_type(4))) float float4v;
typedef __attribute__((ext_vector_type(4))) u16 u16x4;

__device__ __forceinline__ u16 f2bf(float f) {
  union { float f; uint32_t u; } v; v.f = f;
  uint32_t u = v.u;
  return (u16)((u + 0x7FFFu + ((u >> 16) & 1u)) >> 16);
}
__device__ __forceinline__ float bf2f(u16 s) {
  union { uint32_t u; float f; } v; v.u = ((uint32_t)s) << 16; return v.f;
}

__device__ __forceinline__ float fast_exp2(float x) {
#if __has_builtin(__builtin_amdgcn_exp2f)
  return __builtin_amdgcn_exp2f(x);
#else
  return exp2f(x);
#endif
}

// async global->LDS, 16B per lane, dest = wave-uniform base + lane*16
__device__ __forceinline__ void gload16(const u16* g, u16* l) {
  __builtin_amdgcn_global_load_lds((const __attribute__((address_space(1))) void*)g,
                                   (__attribute__((address_space(3))) void*)l,
                                   16, 0, 0);
}

// ---------------- convert f32 -> bf16 ----------------
__global__ __launch_bounds__(256) void k_cvt(const float* __restrict__ in, u16* __restrict__ out, int n4) {
  int i = blockIdx.x * 256 + threadIdx.x;
  if (i >= n4) return;
  float4v v = *(const float4v*)(in + (size_t)i * 4);
  u16x4 o;
  #pragma unroll
  for (int j = 0; j < 4; j++) o[j] = f2bf(v[j]);
  *(u16x4*)(out + (size_t)i * 4) = o;
}

// ---------------- layernorm f32 -> bf16 (one block per row of 1024) ----------------
__global__ __launch_bounds__(256) void k_ln(const float* __restrict__ x, const float* __restrict__ g,
                                            const float* __restrict__ b, u16* __restrict__ out) {
  int row = blockIdx.x, tid = threadIdx.x;
  int wid = tid >> 6;
  const float* xr = x + (size_t)row * 1024;
  float4v v = *(const float4v*)(xr + tid * 4);
  float s = v[0] + v[1] + v[2] + v[3];
  float sq = v[0]*v[0] + v[1]*v[1] + v[2]*v[2] + v[3]*v[3];
  #pragma unroll
  for (int m = 1; m <= 32; m <<= 1) { s += __shfl_xor(s, m); sq += __shfl_xor(sq, m); }
  __shared__ float ss[4], ssq[4];
  if ((tid & 63) == 0) { ss[wid] = s; ssq[wid] = sq; }
  __syncthreads();
  s = ss[0] + ss[1] + ss[2] + ss[3];
  sq = ssq[0] + ssq[1] + ssq[2] + ssq[3];
  float mu = s * (1.0f/1024.0f);
  float var = sq * (1.0f/1024.0f) - mu*mu;
  float rs = rsqrtf(var + 1e-5f);
  u16x4 o;
  #pragma unroll
  for (int j = 0; j < 4; j++) {
    float y = (v[j] - mu) * rs * g[tid*4+j] + b[tid*4+j];
    o[j] = f2bf(y);
  }
  *(u16x4*)(out + (size_t)row * 1024 + tid * 4) = o;
}

// ---------------- GEMM: C[M,N] = A[M,K] @ B[N,K]^T  (bf16 in, fp32 acc) ----------------
// 512 threads / 8 waves (2M x 4N), 128x128 tile, BK=64, double-buffered LDS,
// global_load_lds w=16 (linear dest, inverse-XOR-swizzled source), XCD-chunked swizzle.
// EPI: 1=f32 store + resid, 2=bf16 store gelu(acc+bias), 3=f32 acc+bias+resid, 4=bf16 plain
template<int EPI>
__global__ __launch_bounds__(512) void k_gemm(const u16* __restrict__ A, const u16* __restrict__ B,
                                              const float* __restrict__ bias, const float* __restrict__ resid,
                                              float* __restrict__ Cf, u16* __restrict__ Cb,
                                              int M, int N, int K) {
  __shared__ __align__(16) u16 As[2][8192];
  __shared__ __align__(16) u16 Bs[2][8192];
  int tid = threadIdx.x;
  // bijective XCD-chunked block swizzle (nwg divisible by 8 for all our launches)
  int gx = gridDim.x;
  int lin = blockIdx.y * gx + blockIdx.x;
  int nwg = gx * gridDim.y;
  int cpx = nwg >> 3;
  int swz = (lin & 7) * cpx + (lin >> 3);
  int bx = swz % gx, by = swz / gx;
  int m0 = by * 128, n0 = bx * 128;
  int wid = tid >> 6, lane = tid & 63;
  int wr = wid >> 2, wc = wid & 3;          // wave tile: 64 rows x 32 cols
  int l15 = lane & 15, l16 = lane >> 4;
  // staging geometry: chunk = j*512 + wid*64 + lane ; row = chunk>>3 ; 8 chunks/row
  int srow = wid*8 + (lane >> 3);           // j=0 row; j=1 adds 64 (row&7 unchanged)
  int gslot = (lane & 7) ^ (lane >> 3);     // inverse swizzle on the global source

  f32x4 acc[4][2] = {};
  int nt = K >> 6;

  auto STAGE = [&](int bsel, int kb) {
    const u16* ab = A + (size_t)(m0 + srow) * K + kb + gslot * 8;
    const u16* bb = B + (size_t)(n0 + srow) * K + kb + gslot * 8;
    u16* ad = &As[bsel][wid * 512];
    u16* bd = &Bs[bsel][wid * 512];
    gload16(ab, ad);
    gload16(ab + (size_t)64 * K, ad + 4096);
    gload16(bb, bd);
    gload16(bb + (size_t)64 * K, bd + 4096);
  };

  STAGE(0, 0);
  __syncthreads();
  int cur = 0;
  for (int t = 0; t < nt; ++t) {
    if (t + 1 < nt) STAGE(cur ^ 1, (t + 1) << 6);   // async prefetch over compute
    #pragma unroll
    for (int ks = 0; ks < 2; ks++) {
      short8 af[4], bfr[2];
      #pragma unroll
      for (int m = 0; m < 4; m++) {
        int row = wr*64 + m*16 + l15;
        af[m] = *(const short8*)&As[cur][row*64 + (((ks*4 + l16) ^ (row & 7)) * 8)];
      }
      #pragma unroll
      for (int n = 0; n < 2; n++) {
        int row = wc*32 + n*16 + l15;
        bfr[n] = *(const short8*)&Bs[cur][row*64 + (((ks*4 + l16) ^ (row & 7)) * 8)];
      }
      #pragma unroll
      for (int m = 0; m < 4; m++)
        #pragma unroll
        for (int n = 0; n < 2; n++)
          acc[m][n] = __builtin_amdgcn_mfma_f32_16x16x32_bf16(af[m], bfr[n], acc[m][n], 0, 0, 0);
    }
    __syncthreads();   // drains lgkm + vmcnt: next tile ready, this tile's reads done
    cur ^= 1;
  }

  #pragma unroll
  for (int m = 0; m < 4; m++) {
    #pragma unroll
    for (int n = 0; n < 2; n++) {
      int col = n0 + wc*32 + n*16 + l15;
      #pragma unroll
      for (int r = 0; r < 4; r++) {
        int row = m0 + wr*64 + m*16 + l16*4 + r;
        float v = acc[m][n][r];
        if constexpr (EPI == 1) v += resid[(size_t)row*N + col];
        if constexpr (EPI == 2) { v += bias[col]; v = 0.5f*v*(1.0f + erff(v*0.70710678118f)); }
        if constexpr (EPI == 3) v += bias[col] + resid[(size_t)row*N + col];
        if constexpr (EPI == 2 || EPI == 4) Cb[(size_t)row*N + col] = f2bf(v);
        else Cf[(size_t)row*N + col] = v;
      }
    }
  }
}

// ---------------- prep: l2norm q,k (fold temp*log2e into q), V -> V^T ----------------
__global__ __launch_bounds__(256) void k_prep(const u16* __restrict__ qkv, const float* __restrict__ temp,
                                              u16* __restrict__ Qn, u16* __restrict__ Kn, u16* __restrict__ Vt) {
  int grp = blockIdx.x, bh = blockIdx.y;
  int b = bh >> 4, h = bh & 15;
  int tid = threadIdx.x, wid = tid >> 6, lane = tid & 63;
  int n0 = grp * 64;
  __shared__ __align__(16) u16 vs[64*64];
  float tmp = temp[h] * 1.44269504f;   // fold log2e for exp2-domain softmax
  for (int j = 0; j < 16; j++) {
    int tl = wid + 4*j;
    size_t roff = (size_t)((b*2048) + n0 + tl) * 3072;
    float q = bf2f(qkv[roff + h*64 + lane]);
    float k = bf2f(qkv[roff + 1024 + h*64 + lane]);
    u16 vraw = qkv[roff + 2048 + h*64 + lane];
    float sq = q*q, sk = k*k;
    #pragma unroll
    for (int m = 1; m <= 32; m <<= 1) { sq += __shfl_xor(sq, m); sk += __shfl_xor(sk, m); }
    float qs = tmp / fmaxf(sqrtf(sq), 1e-12f);
    float ksc = 1.0f / fmaxf(sqrtf(sk), 1e-12f);
    size_t obase = ((size_t)bh*2048 + n0 + tl)*64 + lane;
    Qn[obase] = f2bf(q * qs);
    Kn[obase] = f2bf(k * ksc);
    vs[tl*64 + lane] = vraw;
  }
  __syncthreads();
  int d = tid & 63, chunk = tid >> 6;
  u16 vals[16];
  #pragma unroll
  for (int jj = 0; jj < 16; jj++) vals[jj] = vs[(chunk*16 + jj)*64 + d];
  short8 w0, w1v;
  #pragma unroll
  for (int j = 0; j < 8; j++) { w0[j] = (short)vals[j]; w1v[j] = (short)vals[8+j]; }
  size_t vo = ((size_t)bh*64 + d)*2048 + n0 + chunk*16;
  *(short8*)(Vt + vo) = w0;
  *(short8*)(Vt + vo + 8) = w1v;
}

// ---------------- flash attention, swapped-QK^T, fixed-max softmax, dbuf K/V ----------------
__global__ __launch_bounds__(256) void k_attn(const u16* __restrict__ Qn, const u16* __restrict__ Kn,
                                              const u16* __restrict__ Vt, const float* __restrict__ temp,
                                              u16* __restrict__ Out) {
  __shared__ __align__(16) u16 Ks[2][64*64];
  __shared__ __align__(16) u16 Vs[2][64*64];
  __shared__ __align__(16) u16 Ps[4*16*64];
  int qg = blockIdx.x, bh = blockIdx.y;
  int b = bh >> 4, h = bh & 15;
  int tid = threadIdx.x, wid = tid >> 6, lane = tid & 63;
  int l15 = lane & 15, l16 = lane >> 4;
  size_t base = (size_t)bh * 2048 * 64;
  size_t vbase = (size_t)bh * 64 * 2048;
  int q0 = qg*64 + wid*16;
  float m2 = fabsf(temp[h]) * 1.44269504f;
  short8 qf[2];
  #pragma unroll
  for (int ks = 0; ks < 2; ks++)
    qf[ks] = *(const short8*)(Qn + base + (size_t)(q0 + l15)*64 + ks*32 + l16*8);
  f32x4 o[4] = {};
  float lrow = 0.f;
  u16* Pw = Ps + wid*16*64;
  uint32_t* Pw32 = (uint32_t*)Pw;

  auto STAGE = [&](int bsel, int kv0) {
    #pragma unroll
    for (int i = 0; i < 2; i++) {
      int base_row = wid*16 + i*8;
      int row = base_row + (lane >> 3);
      int gslot = (lane & 7) ^ (row & 7);
      gload16(Kn + base + (size_t)(kv0 + row)*64 + gslot*8, &Ks[bsel][base_row*64]);
      gload16(Vt + vbase + (size_t)row*2048 + kv0 + gslot*8, &Vs[bsel][base_row*64]);
    }
  };

  STAGE(0, 0);
  __syncthreads();
  int cur = 0;
  for (int kv0 = 0; kv0 < 2048; kv0 += 64) {
    if (kv0 + 64 < 2048) STAGE(cur ^ 1, kv0 + 64);
    // S^T = K . Q^T : lane holds q = l15, kv = nt*16 + l16*4 + r
    f32x4 s[4] = {};
    #pragma unroll
    for (int ks = 0; ks < 2; ks++) {
      short8 kf[4];
      #pragma unroll
      for (int nt = 0; nt < 4; nt++) {
        int row = nt*16 + l15;
        kf[nt] = *(const short8*)&Ks[cur][row*64 + (((ks*4 + l16) ^ (row&7))*8)];
      }
      #pragma unroll
      for (int nt = 0; nt < 4; nt++)
        s[nt] = __builtin_amdgcn_mfma_f32_16x16x32_bf16(kf[nt], qf[ks], s[nt], 0, 0, 0);
    }
    // fixed-max softmax: p = exp2(s - m2); pack pairs -> P^T rows (q-major) in LDS
    float tsum = 0.f;
    #pragma unroll
    for (int nt = 0; nt < 4; nt++) {
      #pragma unroll
      for (int rp = 0; rp < 2; rp++) {
        float p0 = fast_exp2(s[nt][2*rp]   - m2);
        float p1 = fast_exp2(s[nt][2*rp+1] - m2);
        tsum += p0 + p1;
        uint32_t pk;
        asm("v_cvt_pk_bf16_f32 %0, %1, %2" : "=v"(pk) : "v"(p0), "v"(p1));
        int w = nt*8 + l16*2 + rp;
        int slot = w >> 2;
        Pw32[l15*32 + ((slot ^ (l15 & 7))*4) + (w & 3)] = pk;
      }
    }
    lrow += tsum;
    asm volatile("s_waitcnt lgkmcnt(0)" ::: "memory");
    __builtin_amdgcn_sched_barrier(0);
    // O^T += V^T . P^T
    #pragma unroll
    for (int ks = 0; ks < 2; ks++) {
      short8 pf = *(const short8*)&Pw[l15*64 + (((ks*4 + l16) ^ (l15&7))*8)];
      short8 vf[4];
      #pragma unroll
      for (int dt = 0; dt < 4; dt++) {
        int row = dt*16 + l15;
        vf[dt] = *(const short8*)&Vs[cur][row*64 + (((ks*4 + l16) ^ (row&7))*8)];
      }
      #pragma unroll
      for (int dt = 0; dt < 4; dt++)
        o[dt] = __builtin_amdgcn_mfma_f32_16x16x32_bf16(vf[dt], pf, o[dt], 0, 0, 0);
    }
    __syncthreads();
    cur ^= 1;
  }
  // row sum: lanes sharing l15 hold disjoint kv partials
  lrow += __shfl_xor(lrow, 16);
  lrow += __shfl_xor(lrow, 32);
  float rl = 1.0f / lrow;
  int tok = b*2048 + q0 + l15;
  #pragma unroll
  for (int dt = 0; dt < 4; dt++) {
    u16x4 ov;
    #pragma unroll
    for (int r = 0; r < 4; r++) ov[r] = f2bf(o[dt][r] * rl);
    *(u16x4*)(Out + (size_t)tok*1024 + h*64 + dt*16 + l16*4) = ov;
  }
}

// ---------------- workspace layout (bytes) ----------------
static constexpr size_t OFF_WQKV  = 0;                         // 3072*1024*2
static constexpr size_t OFF_WPROJ = OFF_WQKV  + 6291456;       // 1024*1024*2
static constexpr size_t OFF_W1    = OFF_WPROJ + 2097152;       // 4096*1024*2
static constexpr size_t OFF_W2    = OFF_W1    + 8388608;       // 1024*4096*2
static constexpr size_t OFF_HBF   = OFF_W2    + 8388608;       // 4096*1024*2
static constexpr size_t OFF_H2BF  = OFF_HBF   + 8388608;
static constexpr size_t OFF_QKVBF = OFF_H2BF  + 8388608;       // 4096*3072*2
static constexpr size_t OFF_QN    = OFF_QKVBF + 25165824;      // 32*2048*64*2
static constexpr size_t OFF_KN    = OFF_QN    + 8388608;
static constexpr size_t OFF_VT    = OFF_KN    + 8388608;
static constexpr size_t OFF_AOUT  = OFF_VT    + 8388608;
static constexpr size_t OFF_X1    = OFF_AOUT  + 8388608;       // 4096*1024*4
static constexpr size_t OFF_HID   = OFF_X1    + 16777216;      // 4096*4096*2

extern "C" void kernel_launch(void* const* d_in, const int* in_sizes, int n_in,
                              void* d_out, int out_size, void* d_ws, size_t ws_size,
                              hipStream_t stream) {
  (void)in_sizes; (void)n_in; (void)out_size; (void)ws_size;
  const float* x     = (const float*)d_in[0];
  const float* ln1g  = (const float*)d_in[1];
  const float* ln1b  = (const float*)d_in[2];
  const float* wqkv  = (const float*)d_in[3];
  const float* wproj = (const float*)d_in[4];
  const float* temp  = (const float*)d_in[5];
  const float* ln2g  = (const float*)d_in[6];
  const float* ln2b  = (const float*)d_in[7];
  const float* w1    = (const float*)d_in[8];
  const float* b1    = (const float*)d_in[9];
  const float* w2    = (const float*)d_in[10];
  const float* b2    = (const float*)d_in[11];

  char* ws = (char*)d_ws;
  u16* wqkv_bf  = (u16*)(ws + OFF_WQKV);
  u16* wproj_bf = (u16*)(ws + OFF_WPROJ);
  u16* w1_bf    = (u16*)(ws + OFF_W1);
  u16* w2_bf    = (u16*)(ws + OFF_W2);
  u16* h_bf     = (u16*)(ws + OFF_HBF);
  u16* h2_bf    = (u16*)(ws + OFF_H2BF);
  u16* qkv_bf   = (u16*)(ws + OFF_QKVBF);
  u16* Qn       = (u16*)(ws + OFF_QN);
  u16* Kn       = (u16*)(ws + OFF_KN);
  u16* Vt       = (u16*)(ws + OFF_VT);
  u16* aout_bf  = (u16*)(ws + OFF_AOUT);
  float* x1     = (float*)(ws + OFF_X1);
  u16* hid_bf   = (u16*)(ws + OFF_HID);
  float* outf   = (float*)d_out;

  k_cvt<<<3072, 256, 0, stream>>>(wqkv,  wqkv_bf,  786432);
  k_cvt<<<1024, 256, 0, stream>>>(wproj, wproj_bf, 262144);
  k_cvt<<<4096, 256, 0, stream>>>(w1,    w1_bf,    1048576);
  k_cvt<<<4096, 256, 0, stream>>>(w2,    w2_bf,    1048576);

  k_ln<<<4096, 256, 0, stream>>>(x, ln1g, ln1b, h_bf);
  k_gemm<4><<<dim3(24, 32), 512, 0, stream>>>(h_bf, wqkv_bf, nullptr, nullptr, nullptr, qkv_bf, 4096, 3072, 1024);
  k_prep<<<dim3(32, 32), 256, 0, stream>>>(qkv_bf, temp, Qn, Kn, Vt);
  k_attn<<<dim3(32, 32), 256, 0, stream>>>(Qn, Kn, Vt, temp, aout_bf);
  k_gemm<1><<<dim3(8, 32), 512, 0, stream>>>(aout_bf, wproj_bf, nullptr, x, x1, nullptr, 4096, 1024, 1024);
  k_ln<<<4096, 256, 0, stream>>>(x1, ln2g, ln2b, h2_bf);
  k_gemm<2><<<dim3(32, 32), 512, 0, stream>>>(h2_bf, w1_bf, b1, nullptr, nullptr, hid_bf, 4096, 4096, 1024);
  k_gemm<3><<<dim3(8, 32), 512, 0, stream>>>(hid_bf, w2_bf, b2, x1, outf, nullptr, 4096, 1024, 4096);
}